// Round 3
// baseline (356.974 us; speedup 1.0000x reference)
//
#include <hip/hip_runtime.h>
#include <hip/hip_bf16.h>
#include <hip/hip_cooperative_groups.h>

namespace cg = cooperative_groups;

#define C_   512
#define HS   128
#define NN   10368   // 18*24*24 ; 324 n-tiles of 32

typedef __bf16 bf16x8 __attribute__((ext_vector_type(8)));
typedef __bf16 bf16x4 __attribute__((ext_vector_type(4)));
typedef __bf16 bf16x2 __attribute__((ext_vector_type(2)));
typedef float  f32x4  __attribute__((ext_vector_type(4)));

__device__ __forceinline__ bf16x8 load_f32x8_as_bf16(const float* __restrict__ p) {
    float4 v0 = *(const float4*)p;
    float4 v1 = *(const float4*)(p + 4);
    bf16x8 o;
    o[0] = (__bf16)v0.x; o[1] = (__bf16)v0.y; o[2] = (__bf16)v0.z; o[3] = (__bf16)v0.w;
    o[4] = (__bf16)v1.x; o[5] = (__bf16)v1.y; o[6] = (__bf16)v1.z; o[7] = (__bf16)v1.w;
    return o;
}

// ---------------------------------------------------------------------------
// Single cooperative kernel, 4 phases separated by grid.sync():
//   P0: convert Wj,Wi fp32->bf16 (Wjb,Wib); zero Mtf.
//   P1: per n-tile (32): stage LDS transpose xt[32][520] (verified layout),
//       then 8 waves x 16 h-rows compute
//         fj[h][n]   = sum_c Wj[h][c]*x[c][n] + bj[h]
//         finm[n][h] = sum_c x[c][n]*Wi[h][c] + bi[h]
//       (xt fragment loaded once per kstep, reused as fj's B and finm's A.)
//       xb is GONE: downstream reads feat fp32 + cvt (identical bf16 bits).
//   P2: Mtf[c][h] += sum_n cvt(feat[c][n]) * fj[h][n]  (LDS reduce + atomics)
//   P3: out[c][n] = feat[c][n] + (agg/N) * sum_h Mtf[c][h] * finm[n][h]
// All MFMA index mappings verbatim from the harness-verified round-0/2 code.
// __launch_bounds__(512,4): VGPR<=128 -> 2 blocks/CU -> grid 512 co-resident.
// ---------------------------------------------------------------------------
__global__ __launch_bounds__(512, 4)
void k_all(const float* __restrict__ feat,
           const float* __restrict__ Wi, const float* __restrict__ Wj,
           const float* __restrict__ bi, const float* __restrict__ bj,
           const float* __restrict__ agg,
           __bf16* __restrict__ Wib, __bf16* __restrict__ Wjb,
           __bf16* __restrict__ fj, __bf16* __restrict__ finm,
           float* __restrict__ Mtf, float* __restrict__ out) {
    cg::grid_group grid = cg::this_grid();
    const int t    = threadIdx.x;
    const int nb   = gridDim.x;
    const int gid  = blockIdx.x * 512 + t;
    const int nthr = nb * 512;
    const int lane = t & 63;
    const int l16  = lane & 15;
    const int q    = lane >> 4;
    const int w    = t >> 6;

    __shared__ __align__(16) char shraw[34816];
    __bf16 (*xt)[520]     = (__bf16(*)[520])shraw;       // P1: 32x520 bf16 = 33280 B
    float  (*red)[64][17] = (float(*)[64][17])shraw;     // P2: 8x64x17 f32 = 34816 B

    // ---------------- P0: weight convert + Mtf zero ----------------
    for (int j4 = gid * 4; j4 < 131072; j4 += nthr * 4) {
        const float* src; __bf16* dst; int idx;
        if (j4 < 65536) { src = Wj; dst = Wjb; idx = j4; }
        else            { src = Wi; dst = Wib; idx = j4 - 65536; }
        float4 v = *(const float4*)(src + idx);
        bf16x4 o;
        o[0] = (__bf16)v.x; o[1] = (__bf16)v.y; o[2] = (__bf16)v.z; o[3] = (__bf16)v.w;
        *(bf16x4*)(dst + idx) = o;
    }
    for (int j = gid * 4; j < 65536; j += nthr * 4) {
        f32x4 z = {0.f, 0.f, 0.f, 0.f};
        *(f32x4*)(Mtf + j) = z;
    }
    __threadfence();
    grid.sync();

    // ---------------- P1: stage + G1 + G2 ----------------
    for (int tile = blockIdx.x; tile < 324; tile += nb) {
        const int n0 = tile * 32;
        __syncthreads();                       // xt reuse guard (stride iters)
        {   // stage: n = n0+(t&31), c = 2*(t>>5) + 32p
            const int tn = t & 31;
            const int c2 = (t >> 5) * 2;
            #pragma unroll
            for (int p = 0; p < 16; p++) {
                const int c = p * 32 + c2;
                float v0 = feat[(size_t)c * NN + n0 + tn];
                float v1 = feat[(size_t)(c + 1) * NN + n0 + tn];
                bf16x2 pk; pk[0] = (__bf16)v0; pk[1] = (__bf16)v1;
                *(bf16x2*)&xt[tn][c] = pk;     // 4B-aligned (c even, row 1040B)
            }
        }
        __syncthreads();
        const int h0 = w * 16;
        f32x4 afj[2] = {};                     // fj  : D[row=h][col=n]
        f32x4 afi[2] = {};                     // finm: D[row=n][col=h]
        #pragma unroll 4
        for (int k = 0; k < 512; k += 32) {
            bf16x8 ln0 = *(const bf16x8*)&xt[l16][k + q * 8];
            bf16x8 ln1 = *(const bf16x8*)&xt[16 + l16][k + q * 8];
            bf16x8 wjf = *(const bf16x8*)&Wjb[(size_t)(h0 + l16) * C_ + k + q * 8];
            bf16x8 wif = *(const bf16x8*)&Wib[(size_t)(h0 + l16) * C_ + k + q * 8];
            afj[0] = __builtin_amdgcn_mfma_f32_16x16x32_bf16(wjf, ln0, afj[0], 0, 0, 0);
            afj[1] = __builtin_amdgcn_mfma_f32_16x16x32_bf16(wjf, ln1, afj[1], 0, 0, 0);
            afi[0] = __builtin_amdgcn_mfma_f32_16x16x32_bf16(ln0, wif, afi[0], 0, 0, 0);
            afi[1] = __builtin_amdgcn_mfma_f32_16x16x32_bf16(ln1, wif, afi[1], 0, 0, 0);
        }
        const float4 bjv = *(const float4*)(bj + h0 + q * 4);
        const float  biv = bi[h0 + l16];
        #pragma unroll
        for (int tt = 0; tt < 2; tt++)
            #pragma unroll
            for (int r = 0; r < 4; r++) {
                const int h = h0 + q * 4 + r;
                const int n = n0 + 16 * tt + l16;
                fj[(size_t)h * NN + n] = (__bf16)(afj[tt][r] + (&bjv.x)[r]);
            }
        #pragma unroll
        for (int i2 = 0; i2 < 2; i2++)
            #pragma unroll
            for (int r = 0; r < 4; r++) {
                const int n = n0 + 16 * i2 + q * 4 + r;
                const int h = h0 + l16;
                finm[(size_t)n * HS + h] = (__bf16)(afi[i2][r] + biv);
            }
    }
    __threadfence();
    grid.sync();

    // ---------------- P2: G3 (Mtf += x @ fj^T) ----------------
    for (int bu = blockIdx.x; bu < 512; bu += nb) {
        const int vv    = t >> 6;
        const int tile2 = bu & 63, g = bu >> 6;
        const int c0 = (tile2 >> 2) * 32, hb = (tile2 & 3) * 32;
        const int chunk = g * 8 + vv;                  // 0..63
        const int s0 = (chunk * 324) >> 6;
        const int s1 = ((chunk + 1) * 324) >> 6;
        f32x4 acc[2][2] = {};
        for (int s = s0; s < s1; s++) {
            const int k = s * 32;
            bf16x8 a[2], bb[2];
            a[0]  = load_f32x8_as_bf16(feat + (size_t)(c0 + l16) * NN + k + q * 8);
            a[1]  = load_f32x8_as_bf16(feat + (size_t)(c0 + 16 + l16) * NN + k + q * 8);
            bb[0] = *(const bf16x8*)(fj + (size_t)(hb + l16) * NN + k + q * 8);
            bb[1] = *(const bf16x8*)(fj + (size_t)(hb + 16 + l16) * NN + k + q * 8);
            #pragma unroll
            for (int i = 0; i < 2; i++)
                #pragma unroll
                for (int tt = 0; tt < 2; tt++)
                    acc[i][tt] = __builtin_amdgcn_mfma_f32_16x16x32_bf16(a[i], bb[tt], acc[i][tt], 0, 0, 0);
        }
        __syncthreads();                       // red reuse guard
        #pragma unroll
        for (int i = 0; i < 2; i++)
            #pragma unroll
            for (int tt = 0; tt < 2; tt++)
                #pragma unroll
                for (int r = 0; r < 4; r++)
                    red[vv][lane][i * 8 + tt * 4 + r] = acc[i][tt][r];
        __syncthreads();
        #pragma unroll
        for (int u = 0; u < 2; u++) {
            const int idx = t * 2 + u;
            const int lane_e = idx >> 4, j = idx & 15;
            float s = 0.f;
            #pragma unroll
            for (int z = 0; z < 8; z++) s += red[z][lane_e][j];
            const int i = j >> 3, tt = (j >> 2) & 1, r = j & 3;
            const int qe = lane_e >> 4, le = lane_e & 15;
            const int c = c0 + 16 * i + qe * 4 + r;
            const int h = hb + 16 * tt + le;
            atomicAdd(&Mtf[c * HS + h], s);
        }
    }
    __threadfence();
    grid.sync();

    // ---------------- P3: G4 + scale + residual ----------------
    const int gw = gid >> 6;                   // global wave id
    const int nw = nthr >> 6;
    const float scale = agg[0] * (1.0f / (float)NN);
    for (int u = gw; u < 5184; u += nw) {
        const int c0 = (u & 15) * 32, n0 = (u >> 4) * 32;
        f32x4 acc[2][2] = {};
        #pragma unroll
        for (int k = 0; k < 128; k += 32) {
            bf16x8 a[2], b[2];
            #pragma unroll
            for (int i = 0; i < 2; i++)
                a[i] = load_f32x8_as_bf16(Mtf + (c0 + 16 * i + l16) * HS + k + q * 8);
            #pragma unroll
            for (int tt = 0; tt < 2; tt++)
                b[tt] = *(const bf16x8*)(finm + (size_t)(n0 + 16 * tt + l16) * HS + k + q * 8);
            #pragma unroll
            for (int i = 0; i < 2; i++)
                #pragma unroll
                for (int tt = 0; tt < 2; tt++)
                    acc[i][tt] = __builtin_amdgcn_mfma_f32_16x16x32_bf16(a[i], b[tt], acc[i][tt], 0, 0, 0);
        }
        float fv[2][2][4];
        #pragma unroll
        for (int i = 0; i < 2; i++)
            #pragma unroll
            for (int tt = 0; tt < 2; tt++)
                #pragma unroll
                for (int r = 0; r < 4; r++) {
                    const int c = c0 + 16 * i + q * 4 + r;
                    const int n = n0 + 16 * tt + l16;
                    fv[i][tt][r] = feat[(size_t)c * NN + n];
                }
        #pragma unroll
        for (int i = 0; i < 2; i++)
            #pragma unroll
            for (int tt = 0; tt < 2; tt++)
                #pragma unroll
                for (int r = 0; r < 4; r++) {
                    const int c = c0 + 16 * i + q * 4 + r;
                    const int n = n0 + 16 * tt + l16;
                    out[(size_t)c * NN + n] = fv[i][tt][r] + scale * acc[i][tt][r];
                }
    }
}

// ---------------------------------------------------------------------------
// Workspace layout (bytes):
//   fj   @ 0         : 2,654,208   bf16 [HS][N]
//   finm @ 2,654,208 : 2,654,208   bf16 [N][HS]
//   Mtf  @ 5,308,416 : 262,144     fp32 [C][HS]
//   Wjb  @ 5,570,560 : 131,072     bf16 [HS][C]
//   Wib  @ 5,701,632 : 131,072     bf16 [HS][C]   total ~5.8 MB (xb deleted)
// ---------------------------------------------------------------------------
extern "C" void kernel_launch(void* const* d_in, const int* in_sizes, int n_in,
                              void* d_out, int out_size, void* d_ws, size_t ws_size,
                              hipStream_t stream) {
    const float* feat = (const float*)d_in[0];
    const float* Wi   = (const float*)d_in[1];
    const float* bi   = (const float*)d_in[2];
    const float* Wj   = (const float*)d_in[3];
    const float* bj   = (const float*)d_in[4];
    const float* agg  = (const float*)d_in[5];
    float* out = (float*)d_out;

    char* ws = (char*)d_ws;
    __bf16* fj   = (__bf16*)(ws);
    __bf16* finm = (__bf16*)(ws + 2654208);
    float*  Mtf  = (float*) (ws + 5308416);
    __bf16* Wjb  = (__bf16*)(ws + 5570560);
    __bf16* Wib  = (__bf16*)(ws + 5701632);

    static int nblk = 0;
    if (nblk == 0) {
        int per_cu = 0;
        hipError_t e = hipOccupancyMaxActiveBlocksPerMultiprocessor(
            &per_cu, reinterpret_cast<const void*>(k_all), 512, 0);
        nblk = (e == hipSuccess && per_cu >= 1) ? per_cu * 256 : 256;
        if (nblk > 512) nblk = 512;
    }

    void* args[] = {(void*)&feat, (void*)&Wi, (void*)&Wj, (void*)&bi, (void*)&bj,
                    (void*)&agg, (void*)&Wib, (void*)&Wjb, (void*)&fj, (void*)&finm,
                    (void*)&Mtf, (void*)&out};
    hipLaunchCooperativeKernel(reinterpret_cast<const void*>(k_all),
                               dim3(nblk), dim3(512), args, 0, stream);
}

// Round 4
// 139.669 us; speedup vs baseline: 2.5559x; 2.5559x over previous
//
#include <hip/hip_runtime.h>
#include <hip/hip_bf16.h>

#define C_   512
#define HS   128
#define NN   10368   // 18*24*24 ; 324 n-tiles of 32

typedef __bf16 bf16x8 __attribute__((ext_vector_type(8)));
typedef __bf16 bf16x2 __attribute__((ext_vector_type(2)));
typedef float  f32x4  __attribute__((ext_vector_type(4)));

__device__ __forceinline__ bf16x8 load_f32x8_as_bf16(const float* __restrict__ p) {
    float4 v0 = *(const float4*)p;
    float4 v1 = *(const float4*)(p + 4);
    bf16x8 o;
    o[0] = (__bf16)v0.x; o[1] = (__bf16)v0.y; o[2] = (__bf16)v0.z; o[3] = (__bf16)v0.w;
    o[4] = (__bf16)v1.x; o[5] = (__bf16)v1.y; o[6] = (__bf16)v1.z; o[7] = (__bf16)v1.w;
    return o;
}

// ---------------------------------------------------------------------------
// K1 (fused transpose + G1 + G2) — round-0 verified structure, 340x256:
//   blocks [0,324): per block, n-tile of 32:
//     stage: feat fp32 -> xb bf16 + LDS transposed xt[32][520]; loads BATCHED
//            16 pairs at a time into registers so they pipeline (the round-0
//            version ran at VGPR_Count=32 and serialized every load).
//     compute (4 waves, wave w: h0 = 32w):
//       fj[h][n]   = sum_c Wj[h][c]*x[c][n] + bj[h]   (A=Wj fp32+cvt, B=xt)
//       finm[n][h] = sum_c x[c][n]*Wi[h][c] + bi[h]   (A=xt, B=Wi fp32+cvt)
//       xt fragment loaded ONCE per kstep, reused as fj's B and finm's A.
//   blocks [324,340): zero Mtf (fp32 [C][HS]) for K3's atomics.
//   __launch_bounds__(256,2): 2 blocks/CU (unchanged) but 128-VGPR budget.
// ---------------------------------------------------------------------------
__global__ __launch_bounds__(256, 2)
void k_fused12(const float* __restrict__ feat,
               const float* __restrict__ Wi, const float* __restrict__ Wj,
               const float* __restrict__ bi, const float* __restrict__ bj,
               __bf16* __restrict__ xb, __bf16* __restrict__ fj,
               __bf16* __restrict__ finm, float* __restrict__ Mtf) {
    const int b = blockIdx.x;
    const int t = threadIdx.x;
    if (b >= 324) {                       // zero Mtf: 16 blocks x 256 thr x 16 floats
        const int j = b - 324;
        f32x4 z = {0.f, 0.f, 0.f, 0.f};
        float* p = Mtf + j * 4096 + t * 16;
        *(f32x4*)(p) = z; *(f32x4*)(p + 4) = z;
        *(f32x4*)(p + 8) = z; *(f32x4*)(p + 12) = z;
        return;
    }
    __shared__ __bf16 xt[32][520];
    const int n0 = b * 32;
    // ---- stage: n = n0+(t&31), c = 2*(t>>5) + 16*cc ; two batched passes ----
    {
        const int tn = t & 31;
        const int c2 = (t >> 5) * 2;      // 0..14
        #pragma unroll
        for (int half = 0; half < 2; half++) {
            float va[16], vb[16];
            const int base = half * 256;
            #pragma unroll
            for (int p = 0; p < 16; p++) {
                const int c = base + p * 16 + c2;
                va[p] = feat[(size_t)c * NN + n0 + tn];
                vb[p] = feat[(size_t)(c + 1) * NN + n0 + tn];
            }
            #pragma unroll
            for (int p = 0; p < 16; p++) {
                const int c = base + p * 16 + c2;
                __bf16 b0 = (__bf16)va[p], b1 = (__bf16)vb[p];
                xb[(size_t)c * NN + n0 + tn]       = b0;
                xb[(size_t)(c + 1) * NN + n0 + tn] = b1;
                bf16x2 pk; pk[0] = b0; pk[1] = b1;
                *(bf16x2*)&xt[tn][c] = pk;    // 4B-aligned (c even, row 1040B)
            }
        }
    }
    __syncthreads();
    // ---- compute (round-0 verified mapping) ----
    const int w    = t >> 6;              // 0..3 ; h0 = 32w
    const int lane = t & 63;
    const int l16  = lane & 15;
    const int q    = lane >> 4;
    const int h0   = w * 32;
    f32x4 afj[2][2] = {};                 // fj  : [i=h-16tile][tt=n-16tile]
    f32x4 afi[2][2] = {};                 // finm: [i=n-16tile][tt=h-16tile]
    #pragma unroll 4
    for (int k = 0; k < 512; k += 32) {
        bf16x8 ln[2], wj[2], wi[2];
        #pragma unroll
        for (int i = 0; i < 2; i++)
            ln[i] = *(const bf16x8*)&xt[16 * i + l16][k + q * 8];
        #pragma unroll
        for (int i = 0; i < 2; i++)
            wj[i] = load_f32x8_as_bf16(Wj + (h0 + 16 * i + l16) * 512 + k + q * 8);
        #pragma unroll
        for (int i = 0; i < 2; i++)
            wi[i] = load_f32x8_as_bf16(Wi + (h0 + 16 * i + l16) * 512 + k + q * 8);
        #pragma unroll
        for (int i = 0; i < 2; i++)
            #pragma unroll
            for (int tt = 0; tt < 2; tt++) {
                afj[i][tt] = __builtin_amdgcn_mfma_f32_16x16x32_bf16(wj[i], ln[tt], afj[i][tt], 0, 0, 0);
                afi[i][tt] = __builtin_amdgcn_mfma_f32_16x16x32_bf16(ln[i], wi[tt], afi[i][tt], 0, 0, 0);
            }
    }
    // bias hoist: fj needs bj[h0+16i+q*4+r]; finm needs bi[h0+16tt+l16]
    float4 bjv[2];
    bjv[0] = *(const float4*)(bj + h0 + q * 4);
    bjv[1] = *(const float4*)(bj + h0 + 16 + q * 4);
    float biv[2];
    biv[0] = bi[h0 + l16];
    biv[1] = bi[h0 + 16 + l16];
    #pragma unroll
    for (int i = 0; i < 2; i++)
        #pragma unroll
        for (int tt = 0; tt < 2; tt++)
            #pragma unroll
            for (int r = 0; r < 4; r++) {
                {   // fj: h = h0+16i+q*4+r, n = n0+16tt+l16
                    int h = h0 + 16 * i + q * 4 + r;
                    int n = n0 + 16 * tt + l16;
                    fj[(size_t)h * NN + n] = (__bf16)(afj[i][tt][r] + (&bjv[i].x)[r]);
                }
                {   // finm: n = n0+16i+q*4+r, h = h0+16tt+l16
                    int n = n0 + 16 * i + q * 4 + r;
                    int h = h0 + 16 * tt + l16;
                    finm[(size_t)n * HS + h] = (__bf16)(afi[i][tt][r] + biv[tt]);
                }
            }
}

// ---------------------------------------------------------------------------
// K3 (G3): Mtf[c][h] += sum_n xb[c][n] * fj[h][n]   (fp32 atomics)
//   Round-0 verified geometry: 512 blocks x 256 thr, 64 tiles (32c x 32h) x
//   8 chunk-groups; 4 waves take 4 adjacent K-chunks (~10 ksteps), register
//   double-buffer (round-2 verified), LDS-reduce, 8-way atomicAdd.
// ---------------------------------------------------------------------------
__global__ __launch_bounds__(256, 2)
void k_gemm3(const __bf16* __restrict__ xb, const __bf16* __restrict__ fj,
             float* __restrict__ Mtf) {
    __shared__ float red[4][64][17];
    const int b    = blockIdx.x;
    const int t    = threadIdx.x;
    const int v    = t >> 6;
    const int lane = t & 63;
    const int l16  = lane & 15;
    const int q    = lane >> 4;
    const int tile = b & 63, g = b >> 6;
    const int c0 = (tile >> 2) * 32, h0 = (tile & 3) * 32;
    const int chunk = g * 4 + v;               // 0..31
    const int s0 = (chunk * 324) >> 5;
    const int s1 = ((chunk + 1) * 324) >> 5;
    f32x4 acc[2][2] = {};
    bf16x8 a[2], bb[2];
    {   // preload s0
        const int k = s0 * 32;
        a[0]  = *(const bf16x8*)(xb + (size_t)(c0 + l16) * NN + k + q * 8);
        a[1]  = *(const bf16x8*)(xb + (size_t)(c0 + 16 + l16) * NN + k + q * 8);
        bb[0] = *(const bf16x8*)(fj + (size_t)(h0 + l16) * NN + k + q * 8);
        bb[1] = *(const bf16x8*)(fj + (size_t)(h0 + 16 + l16) * NN + k + q * 8);
    }
    for (int s = s0; s < s1 - 1; s++) {
        const int kn = (s + 1) * 32;
        bf16x8 a2[2], b2[2];
        a2[0] = *(const bf16x8*)(xb + (size_t)(c0 + l16) * NN + kn + q * 8);
        a2[1] = *(const bf16x8*)(xb + (size_t)(c0 + 16 + l16) * NN + kn + q * 8);
        b2[0] = *(const bf16x8*)(fj + (size_t)(h0 + l16) * NN + kn + q * 8);
        b2[1] = *(const bf16x8*)(fj + (size_t)(h0 + 16 + l16) * NN + kn + q * 8);
        #pragma unroll
        for (int i = 0; i < 2; i++)
            #pragma unroll
            for (int tt = 0; tt < 2; tt++)
                acc[i][tt] = __builtin_amdgcn_mfma_f32_16x16x32_bf16(a[i], bb[tt], acc[i][tt], 0, 0, 0);
        a[0] = a2[0]; a[1] = a2[1]; bb[0] = b2[0]; bb[1] = b2[1];
    }
    #pragma unroll
    for (int i = 0; i < 2; i++)
        #pragma unroll
        for (int tt = 0; tt < 2; tt++)
            acc[i][tt] = __builtin_amdgcn_mfma_f32_16x16x32_bf16(a[i], bb[tt], acc[i][tt], 0, 0, 0);
    #pragma unroll
    for (int i = 0; i < 2; i++)
        #pragma unroll
        for (int tt = 0; tt < 2; tt++)
            #pragma unroll
            for (int r = 0; r < 4; r++)
                red[v][lane][i * 8 + tt * 4 + r] = acc[i][tt][r];
    __syncthreads();
    #pragma unroll
    for (int u = 0; u < 4; u++) {
        const int idx = t * 4 + u;
        const int lane_e = idx >> 4, j = idx & 15;
        float s = red[0][lane_e][j] + red[1][lane_e][j]
                + red[2][lane_e][j] + red[3][lane_e][j];
        const int i = j >> 3, tt = (j >> 2) & 1, r = j & 3;
        const int qe = lane_e >> 4, le = lane_e & 15;
        const int c = c0 + 16 * i + qe * 4 + r;
        const int h = h0 + 16 * tt + le;
        atomicAdd(&Mtf[c * HS + h], s);
    }
}

// ---------------------------------------------------------------------------
// K4 (G4 + scale + residual) — round-0 verified geometry (648 blocks, wave
// tile 32c x 64n -> half the Mtf re-reads of the 32n variant):
//   out[c][n] = feat[c][n] + (agg/N) * sum_h Mtf[c][h] * finm[n][h]
//   Residual epilogue BATCHED: all 32 feat loads issued before any store.
// ---------------------------------------------------------------------------
__global__ __launch_bounds__(256, 2)
void k_gemm4(const float* __restrict__ Mtf, const __bf16* __restrict__ finm,
             const float* __restrict__ feat, const float* __restrict__ agg,
             float* __restrict__ out) {
    const int w    = blockIdx.x * 4 + (threadIdx.x >> 6);   // 0..2591
    const int lane = threadIdx.x & 63;
    const int l16  = lane & 15;
    const int q    = lane >> 4;
    const int c0 = (w & 15) * 32, n0 = (w >> 4) * 64;
    const float scale = agg[0] * (1.0f / (float)NN);
    f32x4 acc[2][4] = {};
    #pragma unroll
    for (int k = 0; k < 128; k += 32) {
        bf16x8 a[2], b[4];
        #pragma unroll
        for (int i = 0; i < 2; i++)
            a[i] = load_f32x8_as_bf16(Mtf + (c0 + 16 * i + l16) * HS + k + q * 8);
        #pragma unroll
        for (int tt = 0; tt < 4; tt++)
            b[tt] = *(const bf16x8*)(finm + (size_t)(n0 + 16 * tt + l16) * HS + k + q * 8);
        #pragma unroll
        for (int i = 0; i < 2; i++)
            #pragma unroll
            for (int tt = 0; tt < 4; tt++)
                acc[i][tt] = __builtin_amdgcn_mfma_f32_16x16x32_bf16(a[i], b[tt], acc[i][tt], 0, 0, 0);
    }
    float fv[2][4][4];
    #pragma unroll
    for (int i = 0; i < 2; i++)
        #pragma unroll
        for (int tt = 0; tt < 4; tt++)
            #pragma unroll
            for (int r = 0; r < 4; r++) {
                const int c = c0 + 16 * i + q * 4 + r;
                const int n = n0 + 16 * tt + l16;
                fv[i][tt][r] = feat[(size_t)c * NN + n];
            }
    #pragma unroll
    for (int i = 0; i < 2; i++)
        #pragma unroll
        for (int tt = 0; tt < 4; tt++)
            #pragma unroll
            for (int r = 0; r < 4; r++) {
                const int c = c0 + 16 * i + q * 4 + r;
                const int n = n0 + 16 * tt + l16;
                out[(size_t)c * NN + n] = fv[i][tt][r] + scale * acc[i][tt][r];
            }
}

// ---------------------------------------------------------------------------
// Workspace layout (bytes):
//   xb   @ 0          : 10,616,832   bf16 [C][N]
//   fj   @ 10,616,832 : 2,654,208    bf16 [HS][N]
//   finm @ 13,271,040 : 2,654,208    bf16 [N][HS]
//   Mtf  @ 15,925,248 : 262,144      fp32 [C][HS]   total ~16.2 MB
// ---------------------------------------------------------------------------
extern "C" void kernel_launch(void* const* d_in, const int* in_sizes, int n_in,
                              void* d_out, int out_size, void* d_ws, size_t ws_size,
                              hipStream_t stream) {
    const float* feat = (const float*)d_in[0];
    const float* Wi   = (const float*)d_in[1];
    const float* bi   = (const float*)d_in[2];
    const float* Wj   = (const float*)d_in[3];
    const float* bj   = (const float*)d_in[4];
    const float* agg  = (const float*)d_in[5];
    float* out = (float*)d_out;

    char* ws = (char*)d_ws;
    __bf16* xb   = (__bf16*)(ws);
    __bf16* fj   = (__bf16*)(ws + 10616832);
    __bf16* finm = (__bf16*)(ws + 13271040);
    float*  Mtf  = (float*) (ws + 15925248);

    k_fused12<<<340, 256, 0, stream>>>(feat, Wi, Wj, bi, bj, xb, fj, finm, Mtf);
    k_gemm3 <<<512, 256, 0, stream>>>(xb, fj, Mtf);
    k_gemm4 <<<648, 256, 0, stream>>>(Mtf, finm, feat, agg, out);
}

// Round 5
// 129.241 us; speedup vs baseline: 2.7621x; 1.0807x over previous
//
#include <hip/hip_runtime.h>
#include <hip/hip_bf16.h>

#define C_   512
#define HS   128
#define NN   10368   // 18*24*24 ; 324 n-tiles of 32

typedef __bf16 bf16x8 __attribute__((ext_vector_type(8)));
typedef __bf16 bf16x4 __attribute__((ext_vector_type(4)));
typedef __bf16 bf16x2 __attribute__((ext_vector_type(2)));
typedef float  f32x4  __attribute__((ext_vector_type(4)));

__device__ __forceinline__ bf16x8 load_f32x8_as_bf16(const float* __restrict__ p) {
    float4 v0 = *(const float4*)p;
    float4 v1 = *(const float4*)(p + 4);
    bf16x8 o;
    o[0] = (__bf16)v0.x; o[1] = (__bf16)v0.y; o[2] = (__bf16)v0.z; o[3] = (__bf16)v0.w;
    o[4] = (__bf16)v1.x; o[5] = (__bf16)v1.y; o[6] = (__bf16)v1.z; o[7] = (__bf16)v1.w;
    return o;
}

// ---------------------------------------------------------------------------
// K0 (prep): 20 blocks x 256.
//   b<4 : convert Wj,Wi fp32->bf16 (round-1 verified code).
//   b>=4: zero Mtf fp32 [C][HS] (round-4 verified code).
// ---------------------------------------------------------------------------
__global__ __launch_bounds__(256, 2)
void k_prep(const float* __restrict__ Wi, const float* __restrict__ Wj,
            __bf16* __restrict__ Wib, __bf16* __restrict__ Wjb,
            float* __restrict__ Mtf) {
    const int b = blockIdx.x;
    const int t = threadIdx.x;
    if (b < 4) {   // b=0,1 -> Wjb ; b=2,3 -> Wib
        const float* src = (b < 2) ? Wj : Wi;
        __bf16* dst = (b < 2) ? Wjb : Wib;
        const int off = (b & 1) * 32768;
        #pragma unroll 4
        for (int u = 0; u < 32; u++) {
            const int idx = off + u * 1024 + t * 4;
            float4 v = *(const float4*)(src + idx);
            bf16x4 o;
            o[0] = (__bf16)v.x; o[1] = (__bf16)v.y;
            o[2] = (__bf16)v.z; o[3] = (__bf16)v.w;
            *(bf16x4*)(dst + idx) = o;
        }
    } else {       // zero Mtf: 16 blocks x 256 thr x 16 floats
        const int z = b - 4;
        f32x4 zv = {0.f, 0.f, 0.f, 0.f};
        float* p = Mtf + z * 4096 + t * 16;
        *(f32x4*)(p) = zv; *(f32x4*)(p + 4) = zv;
        *(f32x4*)(p + 8) = zv; *(f32x4*)(p + 12) = zv;
    }
}

// ---------------------------------------------------------------------------
// K1 (fused transpose + G1 + G2), 324 blocks x 256 thr:
//   stage (float4): thread = (n-quad g=t&7, c-lane c8=t>>3); 16 float4 feat
//     loads (128B-contiguous per 8-lane row group), bf16x4 xb stores (8B),
//     scalar LDS scatter into verified xt[32][520] layout.
//   compute (4 waves, wave w: h0 = 32w) — round-0/4 verified mappings:
//     fj[h][n]   = sum_c Wj[h][c]*x[c][n] + bj[h]   (A=Wjb bf16x8, B=xt)
//     finm[n][h] = sum_c x[c][n]*Wi[h][c] + bi[h]   (A=xt, B=Wib bf16x8)
//     weights now PRE-CONVERTED bf16: half the bytes, zero cvt in hot loop.
// ---------------------------------------------------------------------------
__global__ __launch_bounds__(256, 2)
void k_fused12(const float* __restrict__ feat,
               const __bf16* __restrict__ Wib, const __bf16* __restrict__ Wjb,
               const float* __restrict__ bi, const float* __restrict__ bj,
               __bf16* __restrict__ xb, __bf16* __restrict__ fj,
               __bf16* __restrict__ finm) {
    const int b = blockIdx.x;
    const int t = threadIdx.x;
    __shared__ __bf16 xt[32][520];
    const int n0 = b * 32;
    // ---- stage: c = (t>>3) + 32p, n = n0 + 4*(t&7) + j ----
    {
        const int g  = t & 7;          // n-quad
        const int c8 = t >> 3;         // 0..31
        const int nq = 4 * g;
        #pragma unroll
        for (int p = 0; p < 16; p++) {
            const int c = c8 + 32 * p;
            float4 v = *(const float4*)(feat + (size_t)c * NN + n0 + nq);
            bf16x4 o;
            o[0] = (__bf16)v.x; o[1] = (__bf16)v.y;
            o[2] = (__bf16)v.z; o[3] = (__bf16)v.w;
            *(bf16x4*)(xb + (size_t)c * NN + n0 + nq) = o;
            xt[nq + 0][c] = o[0];
            xt[nq + 1][c] = o[1];
            xt[nq + 2][c] = o[2];
            xt[nq + 3][c] = o[3];
        }
    }
    __syncthreads();
    // ---- compute (round-0/4 verified mapping) ----
    const int w    = t >> 6;              // 0..3 ; h0 = 32w
    const int lane = t & 63;
    const int l16  = lane & 15;
    const int q    = lane >> 4;
    const int h0   = w * 32;
    f32x4 afj[2][2] = {};                 // fj  : [i=h-16tile][tt=n-16tile]
    f32x4 afi[2][2] = {};                 // finm: [i=n-16tile][tt=h-16tile]
    #pragma unroll 4
    for (int k = 0; k < 512; k += 32) {
        bf16x8 ln[2], wj[2], wi[2];
        #pragma unroll
        for (int i = 0; i < 2; i++)
            ln[i] = *(const bf16x8*)&xt[16 * i + l16][k + q * 8];
        #pragma unroll
        for (int i = 0; i < 2; i++)
            wj[i] = *(const bf16x8*)&Wjb[(size_t)(h0 + 16 * i + l16) * C_ + k + q * 8];
        #pragma unroll
        for (int i = 0; i < 2; i++)
            wi[i] = *(const bf16x8*)&Wib[(size_t)(h0 + 16 * i + l16) * C_ + k + q * 8];
        #pragma unroll
        for (int i = 0; i < 2; i++)
            #pragma unroll
            for (int tt = 0; tt < 2; tt++) {
                afj[i][tt] = __builtin_amdgcn_mfma_f32_16x16x32_bf16(wj[i], ln[tt], afj[i][tt], 0, 0, 0);
                afi[i][tt] = __builtin_amdgcn_mfma_f32_16x16x32_bf16(ln[i], wi[tt], afi[i][tt], 0, 0, 0);
            }
    }
    float4 bjv[2];
    bjv[0] = *(const float4*)(bj + h0 + q * 4);
    bjv[1] = *(const float4*)(bj + h0 + 16 + q * 4);
    float biv[2];
    biv[0] = bi[h0 + l16];
    biv[1] = bi[h0 + 16 + l16];
    #pragma unroll
    for (int i = 0; i < 2; i++)
        #pragma unroll
        for (int tt = 0; tt < 2; tt++)
            #pragma unroll
            for (int r = 0; r < 4; r++) {
                {   // fj: h = h0+16i+q*4+r, n = n0+16tt+l16
                    int h = h0 + 16 * i + q * 4 + r;
                    int n = n0 + 16 * tt + l16;
                    fj[(size_t)h * NN + n] = (__bf16)(afj[i][tt][r] + (&bjv[i].x)[r]);
                }
                {   // finm: n = n0+16i+q*4+r, h = h0+16tt+l16
                    int n = n0 + 16 * i + q * 4 + r;
                    int h = h0 + 16 * tt + l16;
                    finm[(size_t)n * HS + h] = (__bf16)(afi[i][tt][r] + biv[tt]);
                }
            }
}

// ---------------------------------------------------------------------------
// K2 (G3): Mtf[c][h] += sum_n xb[c][n] * fj[h][n]   (fp32 atomics)
//   Round-4 verbatim (verified): 512 blocks x 256 thr, register dbuf,
//   LDS-reduce, 8-way atomicAdd.
// ---------------------------------------------------------------------------
__global__ __launch_bounds__(256, 2)
void k_gemm3(const __bf16* __restrict__ xb, const __bf16* __restrict__ fj,
             float* __restrict__ Mtf) {
    __shared__ float red[4][64][17];
    const int b    = blockIdx.x;
    const int t    = threadIdx.x;
    const int v    = t >> 6;
    const int lane = t & 63;
    const int l16  = lane & 15;
    const int q    = lane >> 4;
    const int tile = b & 63, g = b >> 6;
    const int c0 = (tile >> 2) * 32, h0 = (tile & 3) * 32;
    const int chunk = g * 4 + v;               // 0..31
    const int s0 = (chunk * 324) >> 5;
    const int s1 = ((chunk + 1) * 324) >> 5;
    f32x4 acc[2][2] = {};
    bf16x8 a[2], bb[2];
    {   // preload s0
        const int k = s0 * 32;
        a[0]  = *(const bf16x8*)(xb + (size_t)(c0 + l16) * NN + k + q * 8);
        a[1]  = *(const bf16x8*)(xb + (size_t)(c0 + 16 + l16) * NN + k + q * 8);
        bb[0] = *(const bf16x8*)(fj + (size_t)(h0 + l16) * NN + k + q * 8);
        bb[1] = *(const bf16x8*)(fj + (size_t)(h0 + 16 + l16) * NN + k + q * 8);
    }
    for (int s = s0; s < s1 - 1; s++) {
        const int kn = (s + 1) * 32;
        bf16x8 a2[2], b2[2];
        a2[0] = *(const bf16x8*)(xb + (size_t)(c0 + l16) * NN + kn + q * 8);
        a2[1] = *(const bf16x8*)(xb + (size_t)(c0 + 16 + l16) * NN + kn + q * 8);
        b2[0] = *(const bf16x8*)(fj + (size_t)(h0 + l16) * NN + kn + q * 8);
        b2[1] = *(const bf16x8*)(fj + (size_t)(h0 + 16 + l16) * NN + kn + q * 8);
        #pragma unroll
        for (int i = 0; i < 2; i++)
            #pragma unroll
            for (int tt = 0; tt < 2; tt++)
                acc[i][tt] = __builtin_amdgcn_mfma_f32_16x16x32_bf16(a[i], bb[tt], acc[i][tt], 0, 0, 0);
        a[0] = a2[0]; a[1] = a2[1]; bb[0] = b2[0]; bb[1] = b2[1];
    }
    #pragma unroll
    for (int i = 0; i < 2; i++)
        #pragma unroll
        for (int tt = 0; tt < 2; tt++)
            acc[i][tt] = __builtin_amdgcn_mfma_f32_16x16x32_bf16(a[i], bb[tt], acc[i][tt], 0, 0, 0);
    #pragma unroll
    for (int i = 0; i < 2; i++)
        #pragma unroll
        for (int tt = 0; tt < 2; tt++)
            #pragma unroll
            for (int r = 0; r < 4; r++)
                red[v][lane][i * 8 + tt * 4 + r] = acc[i][tt][r];
    __syncthreads();
    #pragma unroll
    for (int u = 0; u < 4; u++) {
        const int idx = t * 4 + u;
        const int lane_e = idx >> 4, j = idx & 15;
        float s = red[0][lane_e][j] + red[1][lane_e][j]
                + red[2][lane_e][j] + red[3][lane_e][j];
        const int i = j >> 3, tt = (j >> 2) & 1, r = j & 3;
        const int qe = lane_e >> 4, le = lane_e & 15;
        const int c = c0 + 16 * i + qe * 4 + r;
        const int h = h0 + 16 * tt + le;
        atomicAdd(&Mtf[c * HS + h], s);
    }
}

// ---------------------------------------------------------------------------
// K3 (G4 + scale + residual), 648 blocks x 256 thr:
//   k-loop verbatim round-0/4 (verified): wave tile 32c x 64n, K=128.
//   NEW epilogue: scaled accs -> LDS [128][64] -> re-read so that feat loads
//   and out stores are float4, 64B-contiguous per 4-lane group (fill-like).
// ---------------------------------------------------------------------------
__global__ __launch_bounds__(256, 2)
void k_gemm4(const float* __restrict__ Mtf, const __bf16* __restrict__ finm,
             const float* __restrict__ feat, const float* __restrict__ agg,
             float* __restrict__ out) {
    __shared__ float lds_out[128][64];         // 32 KB
    const int t    = threadIdx.x;
    const int wv   = t >> 6;                   // wave in block
    const int w    = blockIdx.x * 4 + wv;      // 0..2591
    const int lane = t & 63;
    const int l16  = lane & 15;
    const int q    = lane >> 4;
    const int c0 = (w & 15) * 32, n0 = (w >> 4) * 64;
    const float scale = agg[0] * (1.0f / (float)NN);
    f32x4 acc[2][4] = {};
    #pragma unroll
    for (int k = 0; k < 128; k += 32) {
        bf16x8 a[2], bfr[4];
        #pragma unroll
        for (int i = 0; i < 2; i++)
            a[i] = load_f32x8_as_bf16(Mtf + (c0 + 16 * i + l16) * HS + k + q * 8);
        #pragma unroll
        for (int tt = 0; tt < 4; tt++)
            bfr[tt] = *(const bf16x8*)(finm + (size_t)(n0 + 16 * tt + l16) * HS + k + q * 8);
        #pragma unroll
        for (int i = 0; i < 2; i++)
            #pragma unroll
            for (int tt = 0; tt < 4; tt++)
                acc[i][tt] = __builtin_amdgcn_mfma_f32_16x16x32_bf16(a[i], bfr[tt], acc[i][tt], 0, 0, 0);
    }
    // scaled acc -> LDS (row = local c, col = local n)
    #pragma unroll
    for (int i = 0; i < 2; i++)
        #pragma unroll
        for (int tt = 0; tt < 4; tt++)
            #pragma unroll
            for (int r = 0; r < 4; r++)
                lds_out[wv * 32 + 16 * i + q * 4 + r][16 * tt + l16] = scale * acc[i][tt][r];
    __syncthreads();
    // streaming epilogue: thread covers rows {t>>2, t>>2+64}, cols (t&3)*4 + j4*16
    const int c0b = ((blockIdx.x * 4) & 15) * 32;
    const int n0b = ((blockIdx.x * 4) >> 4) * 64;
    #pragma unroll
    for (int rr = 0; rr < 2; rr++) {
        const int row = (t >> 2) + 64 * rr;
        const size_t gbase = (size_t)(c0b + row) * NN + n0b;
        float4 fv[4];
        #pragma unroll
        for (int j4 = 0; j4 < 4; j4++) {
            const int col = (t & 3) * 4 + j4 * 16;
            fv[j4] = *(const float4*)(feat + gbase + col);
        }
        #pragma unroll
        for (int j4 = 0; j4 < 4; j4++) {
            const int col = (t & 3) * 4 + j4 * 16;
            f32x4 v = *(const f32x4*)&lds_out[row][col];
            float4 o;
            o.x = fv[j4].x + v[0]; o.y = fv[j4].y + v[1];
            o.z = fv[j4].z + v[2]; o.w = fv[j4].w + v[3];
            *(float4*)(out + gbase + col) = o;
        }
    }
}

// ---------------------------------------------------------------------------
// Workspace layout (bytes):
//   xb   @ 0          : 10,616,832   bf16 [C][N]
//   fj   @ 10,616,832 : 2,654,208    bf16 [HS][N]
//   finm @ 13,271,040 : 2,654,208    bf16 [N][HS]
//   Mtf  @ 15,925,248 : 262,144      fp32 [C][HS]
//   Wjb  @ 16,187,392 : 131,072      bf16 [HS][C]
//   Wib  @ 16,318,464 : 131,072      bf16 [HS][C]   total ~16.4 MB
// ---------------------------------------------------------------------------
extern "C" void kernel_launch(void* const* d_in, const int* in_sizes, int n_in,
                              void* d_out, int out_size, void* d_ws, size_t ws_size,
                              hipStream_t stream) {
    const float* feat = (const float*)d_in[0];
    const float* Wi   = (const float*)d_in[1];
    const float* bi   = (const float*)d_in[2];
    const float* Wj   = (const float*)d_in[3];
    const float* bj   = (const float*)d_in[4];
    const float* agg  = (const float*)d_in[5];
    float* out = (float*)d_out;

    char* ws = (char*)d_ws;
    __bf16* xb   = (__bf16*)(ws);
    __bf16* fj   = (__bf16*)(ws + 10616832);
    __bf16* finm = (__bf16*)(ws + 13271040);
    float*  Mtf  = (float*) (ws + 15925248);
    __bf16* Wjb  = (__bf16*)(ws + 16187392);
    __bf16* Wib  = (__bf16*)(ws + 16318464);

    k_prep   <<<20,  256, 0, stream>>>(Wi, Wj, Wib, Wjb, Mtf);
    k_fused12<<<324, 256, 0, stream>>>(feat, Wib, Wjb, bi, bj, xb, fj, finm);
    k_gemm3  <<<512, 256, 0, stream>>>(xb, fj, Mtf);
    k_gemm4  <<<648, 256, 0, stream>>>(Mtf, finm, feat, agg, out);
}